// Round 15
// baseline (134.633 us; speedup 1.0000x reference)
//
#include <hip/hip_runtime.h>
#include <hip/hip_bf16.h>

// BahdanauAttention on MI355X (gfx950). ALL float I/O is fp32.
// Internal compute uses bf16 MFMA (no fp32 MFMA on CDNA4).
// Pipeline (4 launches, no separate cast kernel -- casts inlined in staging):
//  K1: EA = exp(2*(query @ W_s^T)) [2048x512], EBT = exp(2*(enc @ Wh^T))^T
//      [512x2048]  (exp-product form: tanh(a+b)=1-2/(1+e^2a e^2b));
//      fp32 inputs cast to bf16 RNE during LDS staging.
//  K2: energies E[t][s] = sum_h (-2 v_h)/(1+EA*EB). Block=(b, 4 t, 128-s grp),
//      wave=64-h slice, lane=2 s. A/v LDS broadcast; B 2-DEEP pipelined
//      coalesced L2 loads (1-deep couldn't hide ~300cyc L3 latency: per-iter
//      compute 232 cyc < latency); paired-rcp.
//  K3: softmax(E, len) -> LDS bf16 weights; ctx = W @ enc [MFMA, fused];
//      enc cast inline during EncT staging.
//  K4: out = tanh([ctx|query] @ W_out^T) [32x64 LDS-tiled MFMA, concat-K];
//      query/Wout cast inline during staging (ctx already bf16).
// d_ws is 256 MiB; harness 0xAA fill (~44 us) is a fixed serialized cost.

typedef __attribute__((ext_vector_type(8))) short bf16x8;
typedef __attribute__((ext_vector_type(4))) float floatx4;

#define C2LOG2E 2.8853900817779268f   // 2*log2(e)
#define LOG2E   1.4426950408889634f
#define NEGBIG  -1e30f

__device__ __forceinline__ float fexp2(float x) { return __builtin_amdgcn_exp2f(x); }
__device__ __forceinline__ float frcp(float x)  { return __builtin_amdgcn_rcpf(x); }
__device__ __forceinline__ float ftanh(float x) {
    return 1.0f - 2.0f * frcp(1.0f + fexp2(C2LOG2E * x));
}
__device__ __forceinline__ float fexp2x(float x) {   // e^{2x}
    return fexp2(C2LOG2E * x);
}

__device__ __forceinline__ unsigned int f2bf_bits(float f) {
    unsigned int u = __float_as_uint(f);
    return (u + 0x7fffu + ((u >> 16) & 1u)) >> 16;   // RNE (inputs finite)
}
__device__ __forceinline__ unsigned int pack2bf(float a, float b) {
    return f2bf_bits(a) | (f2bf_bits(b) << 16);
}
__device__ __forceinline__ uint4 pack8bf(float4 f0, float4 f1) {
    uint4 r;
    r.x = pack2bf(f0.x, f0.y); r.y = pack2bf(f0.z, f0.w);
    r.z = pack2bf(f1.x, f1.y); r.w = pack2bf(f1.z, f1.w);
    return r;
}

// ---- K1: 32x64-tile LDS GEMM, dual-shape: C = exp(2*(X @ W^T)), fp32 in -----
// Part A (blk<512):  X=query[2048x512], W=Ws[512x512],  C=EA  [2048x512]
// Part B (blk>=512): X=Wh[512x512],     W=enc[2048x512],C=EBT [512x2048]
__global__ __launch_bounds__(256) void gemm32x64_exp_dual(
    const float* __restrict__ Xa, const float* __restrict__ Wa,
    float* __restrict__ Ca,
    const float* __restrict__ Xb, const float* __restrict__ Wb_,
    float* __restrict__ Cb)
{
    __shared__ unsigned short sA[32 * 72];
    __shared__ unsigned short sB[64 * 72];
    const int K = 512;
    int blk = blockIdx.x;
    const float* X; const float* W; float* C;
    int mt, nt, N;
    if (blk < 512) { X = Xa; W = Wa; C = Ca; N = 512;  mt = blk >> 3; nt = blk & 7; }
    else { blk -= 512; X = Xb; W = Wb_; C = Cb; N = 2048; mt = blk >> 5; nt = blk & 31; }
    int row0 = mt * 32, col0 = nt * 64;
    int tid = threadIdx.x, lane = tid & 63, w = tid >> 6;
    int srA = tid >> 3, scA = (tid & 7) * 8;
    int srB = tid >> 2, scB = (tid & 3) * 16;
    int mw = (w & 1) * 16, nw = (w >> 1) * 32;
    int r = lane & 15, kq = (lane >> 4) * 8;

    floatx4 acc0 = {0,0,0,0}, acc1 = {0,0,0,0};
    const float* ga = X + (size_t)(row0 + srA) * K + scA;
    const float* gb = W + (size_t)(col0 + srB) * K + scB;

    for (int kb = 0; kb < 8; ++kb) {
        float4 fa0 = ((const float4*)ga)[0], fa1 = ((const float4*)ga)[1];
        float4 fb0 = ((const float4*)gb)[0], fb1 = ((const float4*)gb)[1];
        float4 fb2 = ((const float4*)gb)[2], fb3 = ((const float4*)gb)[3];
        ga += 64; gb += 64;
        uint4 a0 = pack8bf(fa0, fa1);
        uint4 b0 = pack8bf(fb0, fb1);
        uint4 b1 = pack8bf(fb2, fb3);
        __syncthreads();
        *(uint4*)&sA[srA * 72 + scA]     = a0;
        *(uint4*)&sB[srB * 72 + scB]     = b0;
        *(uint4*)&sB[srB * 72 + scB + 8] = b1;
        __syncthreads();
#pragma unroll
        for (int ks = 0; ks < 64; ks += 32) {
            bf16x8 af  = *(const bf16x8*)&sA[(mw + r) * 72 + ks + kq];
            bf16x8 bf0 = *(const bf16x8*)&sB[(nw + r) * 72 + ks + kq];
            bf16x8 bf1 = *(const bf16x8*)&sB[(nw + 16 + r) * 72 + ks + kq];
            acc0 = __builtin_amdgcn_mfma_f32_16x16x32_bf16(af, bf0, acc0, 0, 0, 0);
            acc1 = __builtin_amdgcn_mfma_f32_16x16x32_bf16(af, bf1, acc1, 0, 0, 0);
        }
    }
    int rq = (lane >> 4) * 4;
    float* cp = C + (size_t)(row0 + mw + rq) * N + col0 + nw + r;
#pragma unroll
    for (int i = 0; i < 4; ++i) {
        cp[(size_t)i * N]      = fexp2x(acc0[i]);
        cp[(size_t)i * N + 16] = fexp2x(acc1[i]);
    }
}

// ---- K2: energies. 1024 blocks = (b<<7)|(j<<6)|tq, 512 thr ------------------
// Block: batch b, t-rows tq*4..+3, s-group j (128 s). Early exit: j*128>=len.
// Wave w: h-slice [w*64,w*64+64); lane: s = j*128 + lane + {0,64}.
// E(t,s) = sum_h wn_h/(1+EA*EB), wn=-2v.  A/v LDS broadcast, B 2-deep pipeline.
#define TQ 4
__global__ __launch_bounds__(512) void energies_v7(
    const float* __restrict__ EA,          // [2048][512] e^{2*Ws_q}
    const float* __restrict__ EBT,         // [512][2048] e^{2*Wh_e} transposed
    const float* __restrict__ Vv,          // fp32 512
    const int* __restrict__ Len,
    float* __restrict__ E)                 // fp32 [2048][256]
{
    __shared__ float sA[TQ][516];          // 8.25 KB, uniform broadcast reads
    __shared__ float sWn[512];             // 2 KB  (-2*v)
    __shared__ float sRed[8][TQ][130];     // 16.6 KB

    int tid  = threadIdx.x;
    int lane = tid & 63;
    int w    = tid >> 6;
    int blk  = blockIdx.x;
    int b    = blk >> 7;
    int j    = (blk >> 6) & 1;
    int tq   = blk & 63;                   // low bits -> XCD balance
    int len  = Len[b];
    if (j * 128 >= len) return;            // block-uniform early exit
    int row0g = b * 256 + tq * TQ;

    {   // stage EA rows (4 x 512 fp32) and wn
        int t = tid >> 7, c = (tid & 127) * 4;
        *(float4*)&sA[t][c] = *(const float4*)(EA + (size_t)(row0g + t) * 512 + c);
        sWn[tid] = -2.0f * Vv[tid];
    }
    __syncthreads();

    int h0 = w * 64;
    float acc[TQ][2] = {{0.f}};
    const float* bt = EBT + (size_t)h0 * 2048 + b * 256 + j * 128 + lane;

    // 2-deep software pipeline: B (current), P (+1), PP (+2)
    float B[8], P[8], PP[8];
#pragma unroll
    for (int i = 0; i < 4; ++i) {
        B[i]     = bt[(size_t)i * 2048];
        B[i + 4] = bt[(size_t)i * 2048 + 64];
    }
    {
        const float* nb = bt + (size_t)4 * 2048;
#pragma unroll
        for (int i = 0; i < 4; ++i) {
            P[i]     = nb[(size_t)i * 2048];
            P[i + 4] = nb[(size_t)i * 2048 + 64];
        }
    }
#pragma unroll
    for (int hh = 0; hh < 64; hh += 4) {
        if (hh + 8 < 64) {                 // prefetch 2 iterations ahead
            const float* nb = bt + (size_t)(hh + 8) * 2048;
#pragma unroll
            for (int i = 0; i < 4; ++i) {
                PP[i]     = nb[(size_t)i * 2048];
                PP[i + 4] = nb[(size_t)i * 2048 + 64];
            }
        }
        float4 w4 = *(const float4*)&sWn[h0 + hh];            // LDS broadcast
#pragma unroll
        for (int t = 0; t < TQ; ++t) {
            float4 a4 = *(const float4*)&sA[t][h0 + hh];      // LDS broadcast
#pragma unroll
            for (int u = 0; u < 2; ++u) {                     // 2 s per lane
                float d0 = fmaf(a4.x, B[4 * u + 0], 1.0f);
                float d1 = fmaf(a4.y, B[4 * u + 1], 1.0f);
                float d2 = fmaf(a4.z, B[4 * u + 2], 1.0f);
                float d3 = fmaf(a4.w, B[4 * u + 3], 1.0f);
                float num01 = fmaf(w4.x, d1, w4.y * d0);
                float num23 = fmaf(w4.z, d3, w4.w * d2);
                acc[t][u] = fmaf(num01, frcp(d0 * d1), acc[t][u]);
                acc[t][u] = fmaf(num23, frcp(d2 * d3), acc[t][u]);
            }
        }
#pragma unroll
        for (int i = 0; i < 8; ++i) { B[i] = P[i]; P[i] = PP[i]; }
    }

#pragma unroll
    for (int t = 0; t < TQ; ++t) {
        sRed[w][t][lane]      = acc[t][0];
        sRed[w][t][lane + 64] = acc[t][1];
    }
    __syncthreads();
    {
        int t = tid >> 7, s = tid & 127;   // 512 thr cover 4t x 128s
        float sum = 0.f;
#pragma unroll
        for (int ww = 0; ww < 8; ++ww) sum += sRed[ww][t][s];
        E[(size_t)(row0g + t) * 256 + j * 128 + s] = sum;
    }
}

// ---- K3: fused softmax + ctx GEMM. 256 blocks = (tg<<6)|(hq<<3)|b, 512 thr --
// enc cast fp32->bf16 inline during EncT staging.
__global__ __launch_bounds__(512) void softmax_ctx_fused(
    const float* __restrict__ E,             // fp32 [2048][256]
    const float* __restrict__ Enc,           // fp32 8x256x512
    const int* __restrict__ Len,
    unsigned short* __restrict__ Ctx)        // bf16 2048x512
{
    __shared__ unsigned short EncT[64][264];
    __shared__ unsigned short sWb[64][264];
    int tid = threadIdx.x, lane = tid & 63, w = tid >> 6;
    int blk = blockIdx.x;
    int b = blk & 7, hq = (blk >> 3) & 7, tg = blk >> 6;
    int len = Len[b];

    {   // stage + transpose enc tile: thread (s, 32-h half), fp32 -> bf16
        int s = tid >> 1, hg = (tid & 1) * 32;
        const float4* src = (const float4*)(Enc + (size_t)(b * 256 + s) * 512 + hq * 64 + hg);
#pragma unroll
        for (int k = 0; k < 8; ++k) {
            float4 f = src[k];
            EncT[hg + k * 4 + 0][s] = (unsigned short)f2bf_bits(f.x);
            EncT[hg + k * 4 + 1][s] = (unsigned short)f2bf_bits(f.y);
            EncT[hg + k * 4 + 2][s] = (unsigned short)f2bf_bits(f.z);
            EncT[hg + k * 4 + 3][s] = (unsigned short)f2bf_bits(f.w);
        }
    }
    // softmax: wave w owns rows w*8 .. w*8+7 of the 64-row tile
    for (int i = 0; i < 8; ++i) {
        int row = w * 8 + i;
        const float* erow = E + (size_t)(b * 256 + tg * 64 + row) * 256;
        float ev[4];
#pragma unroll
        for (int j = 0; j < 4; ++j) {
            int s = lane + 64 * j;
            ev[j] = (s < len) ? erow[s] : NEGBIG;
        }
        float m = fmaxf(fmaxf(ev[0], ev[1]), fmaxf(ev[2], ev[3]));
#pragma unroll
        for (int o = 1; o < 64; o <<= 1) m = fmaxf(m, __shfl_xor(m, o, 64));
        float wv[4], wsum = 0.f;
#pragma unroll
        for (int j = 0; j < 4; ++j) { wv[j] = fexp2((ev[j] - m) * LOG2E); wsum += wv[j]; }
#pragma unroll
        for (int o = 1; o < 64; o <<= 1) wsum += __shfl_xor(wsum, o, 64);
        float inv = frcp(wsum);
#pragma unroll
        for (int j = 0; j < 4; ++j)
            sWb[row][lane + 64 * j] = (unsigned short)f2bf_bits(wv[j] * inv);
    }
    __syncthreads();

    int mt = w & 3, npair = w >> 2;          // wave: 16 t x 32 h (2 n-tiles)
    int t0 = mt * 16;
    int r  = lane & 15, kq = (lane >> 4) * 8;
    int n0 = npair * 32 + r;
    floatx4 acc0 = {0.f,0.f,0.f,0.f}, acc1 = {0.f,0.f,0.f,0.f};
#pragma unroll
    for (int k = 0; k < 8; ++k) {
        bf16x8 a  = *(const bf16x8*)(&sWb[t0 + r][kq + 32 * k]);
        bf16x8 b0 = *(const bf16x8*)(&EncT[n0][kq + 32 * k]);
        bf16x8 b1 = *(const bf16x8*)(&EncT[n0 + 16][kq + 32 * k]);
        acc0 = __builtin_amdgcn_mfma_f32_16x16x32_bf16(a, b0, acc0, 0, 0, 0);
        acc1 = __builtin_amdgcn_mfma_f32_16x16x32_bf16(a, b1, acc1, 0, 0, 0);
    }
    int row0 = (lane >> 4) * 4;
    unsigned short* op = Ctx + (size_t)(b * 256 + tg * 64 + t0 + row0) * 512 + hq * 64 + npair * 32 + r;
#pragma unroll
    for (int i = 0; i < 4; ++i) {
        op[i * 512]      = (unsigned short)f2bf_bits(acc0[i]);
        op[i * 512 + 16] = (unsigned short)f2bf_bits(acc1[i]);
    }
}

// ---- K4: 32x64-tile LDS GEMM, concat-K: out = tanh([ctx|q] @ Wout^T) --------
// ctx is bf16; query and Wout are fp32, cast inline during staging.
__global__ __launch_bounds__(256) void out_gemm32x64_tanh(
    const unsigned short* __restrict__ Ctx, const float* __restrict__ Qf,
    const float* __restrict__ Woutf, float* __restrict__ Out)
{
    __shared__ unsigned short sA[32 * 72];
    __shared__ unsigned short sB[64 * 72];
    const int N = 512, KW = 1024;
    int blk = blockIdx.x;
    int mt = blk >> 3, nt = blk & 7;
    int row0 = mt * 32, col0 = nt * 64;
    int tid = threadIdx.x, lane = tid & 63, w = tid >> 6;
    int srA = tid >> 3, scA = (tid & 7) * 8;
    int srB = tid >> 2, scB = (tid & 3) * 16;
    int mw = (w & 1) * 16, nw = (w >> 1) * 32;
    int r = lane & 15, kq = (lane >> 4) * 8;

    floatx4 acc0 = {0,0,0,0}, acc1 = {0,0,0,0};
    const float* gb = Woutf + (size_t)(col0 + srB) * KW + scB;

    for (int kb = 0; kb < 16; ++kb) {
        uint4 a0;
        if (kb < 8) {                      // ctx (bf16)
            a0 = *(const uint4*)(Ctx + (size_t)(row0 + srA) * 512 + kb * 64 + scA);
        } else {                           // query (fp32) -> bf16
            const float* gq = Qf + (size_t)(row0 + srA) * 512 + (kb - 8) * 64 + scA;
            a0 = pack8bf(((const float4*)gq)[0], ((const float4*)gq)[1]);
        }
        float4 fb0 = ((const float4*)gb)[0], fb1 = ((const float4*)gb)[1];
        float4 fb2 = ((const float4*)gb)[2], fb3 = ((const float4*)gb)[3];
        gb += 64;
        uint4 b0 = pack8bf(fb0, fb1);
        uint4 b1 = pack8bf(fb2, fb3);
        __syncthreads();
        *(uint4*)&sA[srA * 72 + scA]     = a0;
        *(uint4*)&sB[srB * 72 + scB]     = b0;
        *(uint4*)&sB[srB * 72 + scB + 8] = b1;
        __syncthreads();
#pragma unroll
        for (int ks = 0; ks < 64; ks += 32) {
            bf16x8 af  = *(const bf16x8*)&sA[(mw + r) * 72 + ks + kq];
            bf16x8 bf0 = *(const bf16x8*)&sB[(nw + r) * 72 + ks + kq];
            bf16x8 bf1 = *(const bf16x8*)&sB[(nw + 16 + r) * 72 + ks + kq];
            acc0 = __builtin_amdgcn_mfma_f32_16x16x32_bf16(af, bf0, acc0, 0, 0, 0);
            acc1 = __builtin_amdgcn_mfma_f32_16x16x32_bf16(af, bf1, acc1, 0, 0, 0);
        }
    }
    int rq = (lane >> 4) * 4;
    float* op = Out + (size_t)(row0 + mw + rq) * N + col0 + nw + r;
#pragma unroll
    for (int i = 0; i < 4; ++i) {
        op[(size_t)i * N]      = ftanh(acc0[i]);
        op[(size_t)i * N + 16] = ftanh(acc1[i]);
    }
}

extern "C" void kernel_launch(void* const* d_in, const int* in_sizes, int n_in,
                              void* d_out, int out_size, void* d_ws, size_t ws_size,
                              hipStream_t stream)
{
    const float* query = (const float*)d_in[0]; // fp32 8x256x512
    const float* enc   = (const float*)d_in[1]; // fp32 8x256x512
    const int*   len   = (const int*)d_in[2];   // int32 8
    const float* Ws    = (const float*)d_in[3]; // fp32 512x512
    const float* Wh    = (const float*)d_in[4]; // fp32 512x512
    const float* v     = (const float*)d_in[5]; // fp32 512
    const float* Wout  = (const float*)d_in[6]; // fp32 512x1024
    float* out = (float*)d_out;                 // fp32 8x256x512

    // d_ws is 256 MiB; layout (~12 MB used)
    float* EA   = (float*)d_ws;                                   // 4 MB [2048][512]
    float* EBT  = EA + 2048 * 512;                                // 4 MB [512][2048]
    float* E    = EBT + 512 * 2048;                               // 2 MB [2048][256]
    unsigned short* ctx = (unsigned short*)(E + 2048 * 256);      // 2 MB [2048][512]

    gemm32x64_exp_dual<<<1024, 256, 0, stream>>>(query, Ws, EA, Wh, enc, EBT);
    energies_v7<<<1024, 512, 0, stream>>>(EA, EBT, v, len, E);
    softmax_ctx_fused<<<256, 512, 0, stream>>>(E, enc, len, ctx);
    out_gemm32x64_tanh<<<512, 256, 0, stream>>>(ctx, query, Wout, out);
}

// Round 16
// 123.148 us; speedup vs baseline: 1.0933x; 1.0933x over previous
//
#include <hip/hip_runtime.h>
#include <hip/hip_bf16.h>

// BahdanauAttention on MI355X (gfx950). ALL float I/O is fp32.
// Internal compute uses bf16 MFMA (no fp32 MFMA on CDNA4).
// Pipeline (5 launches) — R14 configuration (measured best, 123.8 us):
//  K0: cast fp32->bf16 for query/enc/W_s/W_h/W_out into ws
//  K1: EA = exp(2*(query @ W_s^T)) [2048x512], EBT = exp(2*(enc @ Wh^T))^T
//      [512x2048]  (exp-product form: tanh(a+b)=1-2/(1+e^2a e^2b))
//  K2: energies E[t][s] = sum_h (-2 v_h)/(1+EA*EB). Block=(b, 4 t, 128-s grp),
//      wave=64-h slice, lane=2 s. A/v LDS broadcast; B 1-deep pipelined
//      coalesced L2 loads (2-deep regressed in R15: +24 VGPR rotation, and
//      4-block/CU queue already hides latency via TLP); paired-rcp.
//  K3: softmax(E, len) -> LDS bf16 weights; ctx = W @ enc [MFMA, fused]
//  K4: out = tanh([ctx|query] @ W_out^T)  [32x64 LDS-tiled MFMA, concat-K]
// R15 lesson: inline fp32->bf16 casts in GEMM staging sit on the serial
// region between barriers -> dedicated cast kernel is cheaper.
// d_ws is 256 MiB; harness 0xAA fill (~44 us) is a fixed serialized cost.

typedef __attribute__((ext_vector_type(8))) short bf16x8;
typedef __attribute__((ext_vector_type(4))) float floatx4;

#define C2LOG2E 2.8853900817779268f   // 2*log2(e)
#define LOG2E   1.4426950408889634f
#define NEGBIG  -1e30f

__device__ __forceinline__ float fexp2(float x) { return __builtin_amdgcn_exp2f(x); }
__device__ __forceinline__ float frcp(float x)  { return __builtin_amdgcn_rcpf(x); }
__device__ __forceinline__ float ftanh(float x) {
    return 1.0f - 2.0f * frcp(1.0f + fexp2(C2LOG2E * x));
}
__device__ __forceinline__ float fexp2x(float x) {   // e^{2x}
    return fexp2(C2LOG2E * x);
}

__device__ __forceinline__ unsigned int f2bf_bits(float f) {
    unsigned int u = __float_as_uint(f);
    return (u + 0x7fffu + ((u >> 16) & 1u)) >> 16;   // RNE (inputs finite)
}

// ---- K0: cast fp32 -> bf16. 3072 blocks x 256 thr ---------------------------
__global__ __launch_bounds__(256) void cast_all_bf16(
    const float* __restrict__ q,  const float* __restrict__ e,
    const float* __restrict__ Ws, const float* __restrict__ Wh,
    const float* __restrict__ Wo,
    unsigned short* __restrict__ qb,  unsigned short* __restrict__ eb,
    unsigned short* __restrict__ Wsb, unsigned short* __restrict__ Whb,
    unsigned short* __restrict__ Wob)
{
    int blk = blockIdx.x;
    const float* src; unsigned short* dst; int base;
    if      (blk < 1024) { src = q;  dst = qb;  base = blk; }
    else if (blk < 2048) { src = e;  dst = eb;  base = blk - 1024; }
    else if (blk < 2304) { src = Ws; dst = Wsb; base = blk - 2048; }
    else if (blk < 2560) { src = Wh; dst = Whb; base = blk - 2304; }
    else                 { src = Wo; dst = Wob; base = blk - 2560; }
    size_t i = (size_t)base * 1024 + threadIdx.x * 4;
    float4 f = *(const float4*)(src + i);
    ushort4 o;
    o.x = (unsigned short)f2bf_bits(f.x);
    o.y = (unsigned short)f2bf_bits(f.y);
    o.z = (unsigned short)f2bf_bits(f.z);
    o.w = (unsigned short)f2bf_bits(f.w);
    *(ushort4*)(dst + i) = o;
}

// ---- K1: 32x64-tile LDS GEMM, dual-shape: C = exp(2*(X @ W^T)) --------------
// Part A (blk<512):  X=qb[2048x512],  W=Wsb[512x512],  C=EA  [2048x512]
// Part B (blk>=512): X=Whb[512x512],  W=eb[2048x512],  C=EBT [512x2048]
__global__ __launch_bounds__(256) void gemm32x64_exp_dual(
    const unsigned short* __restrict__ Xa, const unsigned short* __restrict__ Wa,
    float* __restrict__ Ca,
    const unsigned short* __restrict__ Xb, const unsigned short* __restrict__ Wb_,
    float* __restrict__ Cb)
{
    __shared__ unsigned short sA[32 * 72];
    __shared__ unsigned short sB[64 * 72];
    const int K = 512;
    int blk = blockIdx.x;
    const unsigned short* X; const unsigned short* W; float* C;
    int mt, nt, N;
    if (blk < 512) { X = Xa; W = Wa; C = Ca; N = 512;  mt = blk >> 3; nt = blk & 7; }
    else { blk -= 512; X = Xb; W = Wb_; C = Cb; N = 2048; mt = blk >> 5; nt = blk & 31; }
    int row0 = mt * 32, col0 = nt * 64;
    int tid = threadIdx.x, lane = tid & 63, w = tid >> 6;
    int srA = tid >> 3, scA = (tid & 7) * 8;
    int srB = tid >> 2, scB = (tid & 3) * 16;
    int mw = (w & 1) * 16, nw = (w >> 1) * 32;
    int r = lane & 15, kq = (lane >> 4) * 8;

    floatx4 acc0 = {0,0,0,0}, acc1 = {0,0,0,0};
    const unsigned short* ga = X + (size_t)(row0 + srA) * K + scA;
    const unsigned short* gb = W + (size_t)(col0 + srB) * K + scB;

    for (int kb = 0; kb < 8; ++kb) {
        uint4 a0 = *(const uint4*)(ga);
        uint4 b0 = *(const uint4*)(gb);
        uint4 b1 = *(const uint4*)(gb + 8);
        ga += 64; gb += 64;
        __syncthreads();
        *(uint4*)&sA[srA * 72 + scA]     = a0;
        *(uint4*)&sB[srB * 72 + scB]     = b0;
        *(uint4*)&sB[srB * 72 + scB + 8] = b1;
        __syncthreads();
#pragma unroll
        for (int ks = 0; ks < 64; ks += 32) {
            bf16x8 af  = *(const bf16x8*)&sA[(mw + r) * 72 + ks + kq];
            bf16x8 bf0 = *(const bf16x8*)&sB[(nw + r) * 72 + ks + kq];
            bf16x8 bf1 = *(const bf16x8*)&sB[(nw + 16 + r) * 72 + ks + kq];
            acc0 = __builtin_amdgcn_mfma_f32_16x16x32_bf16(af, bf0, acc0, 0, 0, 0);
            acc1 = __builtin_amdgcn_mfma_f32_16x16x32_bf16(af, bf1, acc1, 0, 0, 0);
        }
    }
    int rq = (lane >> 4) * 4;
    float* cp = C + (size_t)(row0 + mw + rq) * N + col0 + nw + r;
#pragma unroll
    for (int i = 0; i < 4; ++i) {
        cp[(size_t)i * N]      = fexp2x(acc0[i]);
        cp[(size_t)i * N + 16] = fexp2x(acc1[i]);
    }
}

// ---- K2: energies. 1024 blocks = (b<<7)|(j<<6)|tq, 512 thr ------------------
// Block: batch b, t-rows tq*4..+3, s-group j (128 s). Early exit: j*128>=len.
// Wave w: h-slice [w*64,w*64+64); lane: s = j*128 + lane + {0,64}.
// E(t,s) = sum_h wn_h/(1+EA*EB), wn=-2v.  A/v LDS broadcast, B pipelined.
#define TQ 4
__global__ __launch_bounds__(512) void energies_v6(
    const float* __restrict__ EA,          // [2048][512] e^{2*Ws_q}
    const float* __restrict__ EBT,         // [512][2048] e^{2*Wh_e} transposed
    const float* __restrict__ Vv,          // fp32 512
    const int* __restrict__ Len,
    float* __restrict__ E)                 // fp32 [2048][256]
{
    __shared__ float sA[TQ][516];          // 8.25 KB, uniform broadcast reads
    __shared__ float sWn[512];             // 2 KB  (-2*v)
    __shared__ float sRed[8][TQ][130];     // 16.6 KB

    int tid  = threadIdx.x;
    int lane = tid & 63;
    int w    = tid >> 6;
    int blk  = blockIdx.x;
    int b    = blk >> 7;
    int j    = (blk >> 6) & 1;
    int tq   = blk & 63;                   // low bits -> XCD balance
    int len  = Len[b];
    if (j * 128 >= len) return;            // block-uniform early exit
    int row0g = b * 256 + tq * TQ;

    {   // stage EA rows (4 x 512 fp32) and wn
        int t = tid >> 7, c = (tid & 127) * 4;
        *(float4*)&sA[t][c] = *(const float4*)(EA + (size_t)(row0g + t) * 512 + c);
        sWn[tid] = -2.0f * Vv[tid];
    }
    __syncthreads();

    int h0 = w * 64;
    float acc[TQ][2] = {{0.f}};
    const float* bt = EBT + (size_t)h0 * 2048 + b * 256 + j * 128 + lane;

    // software pipeline: prefetch B for hh=0 (4 h x 2 s-halves)
    float B[8], P[8];
#pragma unroll
    for (int i = 0; i < 4; ++i) {
        B[i]     = bt[(size_t)i * 2048];
        B[i + 4] = bt[(size_t)i * 2048 + 64];
    }
#pragma unroll
    for (int hh = 0; hh < 64; hh += 4) {
        if (hh + 4 < 64) {                 // prefetch next iteration's B
            const float* nb = bt + (size_t)(hh + 4) * 2048;
#pragma unroll
            for (int i = 0; i < 4; ++i) {
                P[i]     = nb[(size_t)i * 2048];
                P[i + 4] = nb[(size_t)i * 2048 + 64];
            }
        }
        float4 w4 = *(const float4*)&sWn[h0 + hh];            // LDS broadcast
#pragma unroll
        for (int t = 0; t < TQ; ++t) {
            float4 a4 = *(const float4*)&sA[t][h0 + hh];      // LDS broadcast
#pragma unroll
            for (int u = 0; u < 2; ++u) {                     // 2 s per lane
                float d0 = fmaf(a4.x, B[4 * u + 0], 1.0f);
                float d1 = fmaf(a4.y, B[4 * u + 1], 1.0f);
                float d2 = fmaf(a4.z, B[4 * u + 2], 1.0f);
                float d3 = fmaf(a4.w, B[4 * u + 3], 1.0f);
                float num01 = fmaf(w4.x, d1, w4.y * d0);
                float num23 = fmaf(w4.z, d3, w4.w * d2);
                acc[t][u] = fmaf(num01, frcp(d0 * d1), acc[t][u]);
                acc[t][u] = fmaf(num23, frcp(d2 * d3), acc[t][u]);
            }
        }
#pragma unroll
        for (int i = 0; i < 8; ++i) B[i] = P[i];
    }

#pragma unroll
    for (int t = 0; t < TQ; ++t) {
        sRed[w][t][lane]      = acc[t][0];
        sRed[w][t][lane + 64] = acc[t][1];
    }
    __syncthreads();
    {
        int t = tid >> 7, s = tid & 127;   // 512 thr cover 4t x 128s
        float sum = 0.f;
#pragma unroll
        for (int ww = 0; ww < 8; ++ww) sum += sRed[ww][t][s];
        E[(size_t)(row0g + t) * 256 + j * 128 + s] = sum;
    }
}

// ---- K3: fused softmax + ctx GEMM. 256 blocks = (tg<<6)|(hq<<3)|b, 512 thr --
__global__ __launch_bounds__(512) void softmax_ctx_fused(
    const float* __restrict__ E,             // fp32 [2048][256]
    const unsigned short* __restrict__ Eb,   // bf16 8x256x512
    const int* __restrict__ Len,
    unsigned short* __restrict__ Ctx)        // bf16 2048x512
{
    __shared__ unsigned short EncT[64][264];
    __shared__ unsigned short sWb[64][264];
    int tid = threadIdx.x, lane = tid & 63, w = tid >> 6;
    int blk = blockIdx.x;
    int b = blk & 7, hq = (blk >> 3) & 7, tg = blk >> 6;
    int len = Len[b];

    {   // stage + transpose enc tile: thread (s, 32-h half)
        int s = tid >> 1, hg = (tid & 1) * 32;
        const ushort4* src = (const ushort4*)(Eb + (size_t)(b * 256 + s) * 512 + hq * 64 + hg);
#pragma unroll
        for (int k = 0; k < 8; ++k) {
            ushort4 u = src[k];
            EncT[hg + k * 4 + 0][s] = u.x;
            EncT[hg + k * 4 + 1][s] = u.y;
            EncT[hg + k * 4 + 2][s] = u.z;
            EncT[hg + k * 4 + 3][s] = u.w;
        }
    }
    // softmax: wave w owns rows w*8 .. w*8+7 of the 64-row tile
    for (int i = 0; i < 8; ++i) {
        int row = w * 8 + i;
        const float* erow = E + (size_t)(b * 256 + tg * 64 + row) * 256;
        float ev[4];
#pragma unroll
        for (int j = 0; j < 4; ++j) {
            int s = lane + 64 * j;
            ev[j] = (s < len) ? erow[s] : NEGBIG;
        }
        float m = fmaxf(fmaxf(ev[0], ev[1]), fmaxf(ev[2], ev[3]));
#pragma unroll
        for (int o = 1; o < 64; o <<= 1) m = fmaxf(m, __shfl_xor(m, o, 64));
        float wv[4], wsum = 0.f;
#pragma unroll
        for (int j = 0; j < 4; ++j) { wv[j] = fexp2((ev[j] - m) * LOG2E); wsum += wv[j]; }
#pragma unroll
        for (int o = 1; o < 64; o <<= 1) wsum += __shfl_xor(wsum, o, 64);
        float inv = frcp(wsum);
#pragma unroll
        for (int j = 0; j < 4; ++j)
            sWb[row][lane + 64 * j] = (unsigned short)f2bf_bits(wv[j] * inv);
    }
    __syncthreads();

    int mt = w & 3, npair = w >> 2;          // wave: 16 t x 32 h (2 n-tiles)
    int t0 = mt * 16;
    int r  = lane & 15, kq = (lane >> 4) * 8;
    int n0 = npair * 32 + r;
    floatx4 acc0 = {0.f,0.f,0.f,0.f}, acc1 = {0.f,0.f,0.f,0.f};
#pragma unroll
    for (int k = 0; k < 8; ++k) {
        bf16x8 a  = *(const bf16x8*)(&sWb[t0 + r][kq + 32 * k]);
        bf16x8 b0 = *(const bf16x8*)(&EncT[n0][kq + 32 * k]);
        bf16x8 b1 = *(const bf16x8*)(&EncT[n0 + 16][kq + 32 * k]);
        acc0 = __builtin_amdgcn_mfma_f32_16x16x32_bf16(a, b0, acc0, 0, 0, 0);
        acc1 = __builtin_amdgcn_mfma_f32_16x16x32_bf16(a, b1, acc1, 0, 0, 0);
    }
    int row0 = (lane >> 4) * 4;
    unsigned short* op = Ctx + (size_t)(b * 256 + tg * 64 + t0 + row0) * 512 + hq * 64 + npair * 32 + r;
#pragma unroll
    for (int i = 0; i < 4; ++i) {
        op[i * 512]      = (unsigned short)f2bf_bits(acc0[i]);
        op[i * 512 + 16] = (unsigned short)f2bf_bits(acc1[i]);
    }
}

// ---- K4: 32x64-tile LDS GEMM, concat-K: out = tanh([ctx|q] @ Wout^T) --------
__global__ __launch_bounds__(256) void out_gemm32x64_tanh(
    const unsigned short* __restrict__ Ctx, const unsigned short* __restrict__ Q,
    const unsigned short* __restrict__ Wout, float* __restrict__ Out)
{
    __shared__ unsigned short sA[32 * 72];
    __shared__ unsigned short sB[64 * 72];
    const int N = 512, KW = 1024;
    int blk = blockIdx.x;
    int mt = blk >> 3, nt = blk & 7;
    int row0 = mt * 32, col0 = nt * 64;
    int tid = threadIdx.x, lane = tid & 63, w = tid >> 6;
    int srA = tid >> 3, scA = (tid & 7) * 8;
    int srB = tid >> 2, scB = (tid & 3) * 16;
    int mw = (w & 1) * 16, nw = (w >> 1) * 32;
    int r = lane & 15, kq = (lane >> 4) * 8;

    floatx4 acc0 = {0,0,0,0}, acc1 = {0,0,0,0};
    const unsigned short* gb = Wout + (size_t)(col0 + srB) * KW + scB;

    for (int kb = 0; kb < 16; ++kb) {
        const unsigned short* asrc = (kb < 8 ? Ctx : Q);
        const unsigned short* ga = asrc + (size_t)(row0 + srA) * 512 + (kb & 7) * 64 + scA;
        uint4 a0 = *(const uint4*)(ga);
        uint4 b0 = *(const uint4*)(gb);
        uint4 b1 = *(const uint4*)(gb + 8);
        gb += 64;
        __syncthreads();
        *(uint4*)&sA[srA * 72 + scA]     = a0;
        *(uint4*)&sB[srB * 72 + scB]     = b0;
        *(uint4*)&sB[srB * 72 + scB + 8] = b1;
        __syncthreads();
#pragma unroll
        for (int ks = 0; ks < 64; ks += 32) {
            bf16x8 af  = *(const bf16x8*)&sA[(mw + r) * 72 + ks + kq];
            bf16x8 bf0 = *(const bf16x8*)&sB[(nw + r) * 72 + ks + kq];
            bf16x8 bf1 = *(const bf16x8*)&sB[(nw + 16 + r) * 72 + ks + kq];
            acc0 = __builtin_amdgcn_mfma_f32_16x16x32_bf16(af, bf0, acc0, 0, 0, 0);
            acc1 = __builtin_amdgcn_mfma_f32_16x16x32_bf16(af, bf1, acc1, 0, 0, 0);
        }
    }
    int rq = (lane >> 4) * 4;
    float* op = Out + (size_t)(row0 + mw + rq) * N + col0 + nw + r;
#pragma unroll
    for (int i = 0; i < 4; ++i) {
        op[(size_t)i * N]      = ftanh(acc0[i]);
        op[(size_t)i * N + 16] = ftanh(acc1[i]);
    }
}

extern "C" void kernel_launch(void* const* d_in, const int* in_sizes, int n_in,
                              void* d_out, int out_size, void* d_ws, size_t ws_size,
                              hipStream_t stream)
{
    const float* query = (const float*)d_in[0]; // fp32 8x256x512
    const float* enc   = (const float*)d_in[1]; // fp32 8x256x512
    const int*   len   = (const int*)d_in[2];   // int32 8
    const float* Ws    = (const float*)d_in[3]; // fp32 512x512
    const float* Wh    = (const float*)d_in[4]; // fp32 512x512
    const float* v     = (const float*)d_in[5]; // fp32 512
    const float* Wout  = (const float*)d_in[6]; // fp32 512x1024
    float* out = (float*)d_out;                 // fp32 8x256x512

    // d_ws is 256 MiB; generous non-aliased layout (~20 MB used)
    float* EA   = (float*)d_ws;                                   // 4 MB [2048][512]
    float* EBT  = EA + 2048 * 512;                                // 4 MB [512][2048]
    float* E    = EBT + 512 * 2048;                               // 2 MB [2048][256]
    unsigned short* qb  = (unsigned short*)(E + 2048 * 256);      // 2 MB
    unsigned short* eb  = qb + 2048 * 512;                        // 2 MB
    unsigned short* Wsb = eb + 2048 * 512;                        // 0.5 MB
    unsigned short* Whb = Wsb + 512 * 512;                        // 0.5 MB
    unsigned short* Wob = Whb + 512 * 512;                        // 1 MB
    unsigned short* ctx = Wob + 512 * 1024;                       // 2 MB

    cast_all_bf16<<<3072, 256, 0, stream>>>(query, enc, Ws, Wh, Wout,
                                            qb, eb, Wsb, Whb, Wob);
    gemm32x64_exp_dual<<<1024, 256, 0, stream>>>(qb, Wsb, EA, Whb, eb, EBT);
    energies_v6<<<1024, 512, 0, stream>>>(EA, EBT, v, len, E);
    softmax_ctx_fused<<<256, 512, 0, stream>>>(E, eb, len, ctx);
    out_gemm32x64_tanh<<<512, 256, 0, stream>>>(ctx, qb, Wob, out);
}